// Round 6
// baseline (226.120 us; speedup 1.0000x reference)
//
#include <hip/hip_runtime.h>
#include <hip/hip_bf16.h>
#include <stdint.h>

#define TSEQ 2048
#define DMODEL 1024

typedef __attribute__((ext_vector_type(8))) short bf16x8;
typedef __attribute__((ext_vector_type(4))) float f32x4;
typedef __attribute__((ext_vector_type(16))) float f32x16;

union Frag { bf16x8 v; uint4 q; };

__device__ __forceinline__ uint16_t f2bfu(float f) {
  uint32_t u = __builtin_bit_cast(uint32_t, f);
  u += 0x7fffu + ((u >> 16) & 1u);
  return (uint16_t)(u >> 16);
}

__device__ __forceinline__ uint32_t pk2bf(float a, float b) {
  return ((uint32_t)f2bfu(b) << 16) | f2bfu(a);
}

__device__ __forceinline__ float fexp2(float x) {
#if __has_builtin(__builtin_amdgcn_exp2f)
  return __builtin_amdgcn_exp2f(x);
#else
  return exp2f(x);
#endif
}

__device__ __forceinline__ void gload_lds16(const void* g, void* l) {
  __builtin_amdgcn_global_load_lds(
      (const __attribute__((address_space(1))) void*)g,
      (__attribute__((address_space(3))) void*)l, 16, 0, 0);
}

// ---------------- prep kernels ----------------

__global__ __launch_bounds__(256) void cvt_x_kernel(const float* __restrict__ x,
                                                    uint16_t* __restrict__ xb, int n4) {
  int i = blockIdx.x * 256 + threadIdx.x;
  if (i >= n4) return;
  float4 v = ((const float4*)x)[i];
  ushort4 o;
  o.x = f2bfu(v.x); o.y = f2bfu(v.y); o.z = f2bfu(v.z); o.w = f2bfu(v.w);
  ((ushort4*)xb)[i] = o;
}

// dst[n][k] = src[k][n], fp32 -> bf16.  Wq gets 0.125*log2(e) folded in (exp2 softmax).
__global__ __launch_bounds__(256) void cvt_w_kernel(const float* __restrict__ Wq,
    const float* __restrict__ Wk, const float* __restrict__ Wv, const float* __restrict__ Wo,
    uint16_t* __restrict__ Wqkvt, uint16_t* __restrict__ Wot) {
  const float* src = (blockIdx.z == 0) ? Wq : (blockIdx.z == 1) ? Wk
                   : (blockIdx.z == 2) ? Wv : Wo;
  uint16_t* dst = (blockIdx.z < 3) ? (Wqkvt + (size_t)blockIdx.z * DMODEL * DMODEL) : Wot;
  const float wscale = (blockIdx.z == 0) ? 0.125f * 1.4426950408889634f : 1.0f;
  __shared__ float tile[32][33];
  const int x0 = blockIdx.x * 32, y0 = blockIdx.y * 32;
  for (int ii = 0; ii < 4; ii++) {
    int i = threadIdx.y + ii * 8;
    tile[i][threadIdx.x] = src[(size_t)(y0 + i) * DMODEL + x0 + threadIdx.x];
  }
  __syncthreads();
  for (int ii = 0; ii < 4; ii++) {
    int i = threadIdx.y + ii * 8;
    dst[(size_t)(x0 + i) * DMODEL + y0 + threadIdx.x] = f2bfu(tile[threadIdx.x][i] * wscale);
  }
}

// ------- 128x128 GEMM core: 2-phase dbuf, counted vmcnt (T3 minimum) -------
// A row-major [*,1024] bf16, B = W^T rows.  LDS 32 KB (2 x 8KB A + 2 x 8KB B).
// Static x2 unroll: buffer choice is compile-time (rule #20 safe).

__device__ __forceinline__ void gemm_stage(const char* Ab, const char* Bb, int kk,
                                           char* ldsA, char* ldsB, int wave, int lane) {
  const int srow = lane >> 2;        // 0..15 within a 16-row chunk
  const int scol = (lane & 3) * 16;  // byte col within 64B row
#pragma unroll
  for (int c4 = 0; c4 < 2; ++c4) {
    const int c = wave * 2 + c4;     // chunk 0..7 of each tile
    gload_lds16(Ab + (size_t)(c * 16 + srow) * 2048 + kk * 2 + scol, ldsA + c * 1024);
    gload_lds16(Bb + (size_t)(c * 16 + srow) * 2048 + kk * 2 + scol, ldsB + c * 1024);
  }
}

__device__ __forceinline__ void gemm_compute(const char* ldsA, const char* ldsB,
                                             int wm0, int wn0, int lr, int lg,
                                             f32x4 (&acc)[4][4]) {
  Frag a[4], b[4];
#pragma unroll
  for (int mi = 0; mi < 4; mi++)
    a[mi].q = *(const uint4*)(ldsA + (wm0 + mi * 16 + lr) * 64 + lg * 16);
#pragma unroll
  for (int ni = 0; ni < 4; ni++)
    b[ni].q = *(const uint4*)(ldsB + (wn0 + ni * 16 + lr) * 64 + lg * 16);
#pragma unroll
  for (int mi = 0; mi < 4; mi++)
#pragma unroll
    for (int ni = 0; ni < 4; ni++)
      acc[mi][ni] = __builtin_amdgcn_mfma_f32_16x16x32_bf16(a[mi].v, b[ni].v,
                                                            acc[mi][ni], 0, 0, 0);
}

__device__ __forceinline__ void gemm128_core(const char* Ab, const char* Bb,
                                             char* lds,  // 32768 bytes
                                             f32x4 (&acc)[4][4]) {
  const int tid = threadIdx.x;
  const int wave = tid >> 6, lane = tid & 63;
  const int lr = lane & 15, lg = lane >> 4;
  const int wm0 = (wave >> 1) * 64, wn0 = (wave & 1) * 64;
  char* const A0 = lds;          char* const B0 = lds + 8192;
  char* const A1 = lds + 16384;  char* const B1 = lds + 24576;

#pragma unroll
  for (int i = 0; i < 4; i++)
#pragma unroll
    for (int j = 0; j < 4; j++) acc[i][j] = (f32x4){0.f, 0.f, 0.f, 0.f};

  gemm_stage(Ab, Bb, 0, A0, B0, wave, lane);
  for (int it = 0; it < 32; it += 2) {
    // ---- even step: compute buf0, prefetch (it+1) into buf1 ----
    gemm_stage(Ab, Bb, (it + 1) * 32, A1, B1, wave, lane);
    asm volatile("s_waitcnt vmcnt(4)" ::: "memory");  // buf0 landed; buf1 in flight
    __builtin_amdgcn_s_barrier();
    __builtin_amdgcn_sched_barrier(0);
    gemm_compute(A0, B0, wm0, wn0, lr, lg, acc);
    __builtin_amdgcn_s_barrier();                     // buf0 fully consumed

    // ---- odd step: compute buf1, prefetch (it+2) into buf0 ----
    if (it + 2 < 32) {
      gemm_stage(Ab, Bb, (it + 2) * 32, A0, B0, wave, lane);
      asm volatile("s_waitcnt vmcnt(4)" ::: "memory");
    } else {
      asm volatile("s_waitcnt vmcnt(0)" ::: "memory");
    }
    __builtin_amdgcn_s_barrier();
    __builtin_amdgcn_sched_barrier(0);
    gemm_compute(A1, B1, wm0, wn0, lr, lg, acc);
    __builtin_amdgcn_s_barrier();                     // buf1 fully consumed
  }
}

// ---------------- QKV projection GEMM, scatter epilogue ----------------

__global__ __launch_bounds__(256) void gemm_qkv_kernel(const uint16_t* __restrict__ Xb,
    const uint16_t* __restrict__ Wt, uint16_t* __restrict__ Qo,
    uint16_t* __restrict__ Ko, uint16_t* __restrict__ Vt) {
  __shared__ __align__(16) char lds[32768];
  // bijective XCD swizzle: 1536 blocks = 8 chunks x 192 (m fastest within chunk)
  const int wg = (blockIdx.x & 7) * 192 + (blockIdx.x >> 3);
  const int m0 = (wg & 63) * 128;
  const int n0 = (wg >> 6) * 128;
  f32x4 acc[4][4];
  gemm128_core((const char*)Xb + (size_t)m0 * 2048, (const char*)Wt + (size_t)n0 * 2048,
               lds, acc);

  const int tid = threadIdx.x, wave = tid >> 6, lane = tid & 63;
  const int lr = lane & 15, lg = lane >> 4;
  const int wm0 = (wave >> 1) * 64, wn0 = (wave & 1) * 64;
#pragma unroll
  for (int mi = 0; mi < 4; mi++)
#pragma unroll
    for (int ni = 0; ni < 4; ni++) {
      const int col = n0 + wn0 + ni * 16 + lr;
      const int p = col >> 10, c = col & 1023, h = c >> 6, d = c & 63;
#pragma unroll
      for (int r = 0; r < 4; r++) {
        const int row = m0 + wm0 + mi * 16 + 4 * lg + r;
        const int bb = row >> 11, t = row & 2047;
        const int bh = bb * 16 + h;
        const uint16_t val = f2bfu(acc[mi][ni][r]);
        if (p == 0)      Qo[((size_t)bh * TSEQ + t) * 64 + d] = val;
        else if (p == 1) Ko[((size_t)bh * TSEQ + t) * 64 + d] = val;
        else             Vt[((size_t)bh * 64 + d) * TSEQ + t] = val;
      }
    }
}

// ---------------- flash attention (swapped-QK^T, 32x32 MFMA) ----------------
// 1 block = 128 q rows of one (b,h); 4 waves x 32 q rows (lane&31 = q column).
// KV tile = 64; K tile [64kv][128B], V^T tile [64d][128B], both XOR-swizzled,
// double-buffered via global_load_lds with counted vmcnt.
// NOTE: all private arrays indexed with compile-time constants only (rule #20).

__device__ __forceinline__ void stage_kv(const char* Kb, const char* Vb, int kv0,
                                         char* kdst, char* vdst, int tid) {
  const int w1024 = (tid >> 6) * 1024;
#pragma unroll
  for (int i = 0; i < 2; i++) {
    const int o = i * 4096 + tid * 16;
    const int row = o >> 7;
    const int scol = (o & 127) ^ ((row & 7) << 4);
    gload_lds16(Kb + (size_t)(kv0 + row) * 128 + scol, kdst + i * 4096 + w1024);
    gload_lds16(Vb + (size_t)row * 4096 + kv0 * 2 + scol, vdst + i * 4096 + w1024);
  }
}

__global__ __launch_bounds__(256, 3) void attn_kernel(const uint16_t* __restrict__ Qw,
    const uint16_t* __restrict__ Kw, const uint16_t* __restrict__ Vtw,
    uint16_t* __restrict__ Ctx) {
  const int bid = blockIdx.x;
  const int qt = 15 - (bid >> 6);   // heavy blocks dispatched first
  const int bh = bid & 63;
  const int tid = threadIdx.x;
  const int w = tid >> 6, lane = tid & 63;
  const int lq = lane & 31;         // this lane's q row (within wave tile)
  const int hi = lane >> 5;
  const int wq0 = qt * 128 + w * 32;

  const char* Qb = (const char*)Qw + (size_t)bh * TSEQ * 128;
  const char* Kb = (const char*)Kw + (size_t)bh * TSEQ * 128;
  const char* Vb = (const char*)Vtw + (size_t)bh * 64 * 4096;

  __shared__ __align__(16) char kbuf[2][8192];
  __shared__ __align__(16) char vbuf[2][8192];

  // Q as B-operand fragments: col=q=lane&31, k = kc*16 + 8*hi + e
  Frag qa[4];
#pragma unroll
  for (int kc = 0; kc < 4; kc++)
    qa[kc].q = *(const uint4*)(Qb + (size_t)(wq0 + lq) * 128 + kc * 32 + hi * 16);

  f32x16 o0 = 0.f, o1 = 0.f;   // O^T: col=q (lane), row=d
  float mrun = -1e30f, lrun = 0.f;

  const int nt = 2 * qt + 2;
  stage_kv(Kb, Vb, 0, kbuf[0], vbuf[0], tid);
  int cur = 0;
  for (int t = 0; t < nt; ++t) {
    const int kv0 = t * 64;
    if (t + 1 < nt) {
      stage_kv(Kb, Vb, kv0 + 64, kbuf[cur ^ 1], vbuf[cur ^ 1], tid);
      asm volatile("s_waitcnt vmcnt(4)" ::: "memory");
    } else {
      asm volatile("s_waitcnt vmcnt(0)" ::: "memory");
    }
    __builtin_amdgcn_s_barrier();
    __builtin_amdgcn_sched_barrier(0);

    if (kv0 <= wq0 + 31) {
      const char* Kt = kbuf[cur];
      const char* Vt = vbuf[cur];
      // ---- S^T = K Q^T : per lane one q col, 32 kv rows over 2 halves ----
      f32x16 s[2];
#pragma unroll
      for (int kvh = 0; kvh < 2; kvh++) {
        f32x16 acc = 0.f;
#pragma unroll
        for (int kc = 0; kc < 4; kc++) {
          const int row = kvh * 32 + lq;
          Frag kf;
          kf.q = *(const uint4*)(Kt + row * 128 + ((kc * 32 + hi * 16) ^ ((row & 7) << 4)));
          acc = __builtin_amdgcn_mfma_f32_32x32x16_bf16(kf.v, qa[kc].v, acc, 0, 0, 0);
        }
        s[kvh] = acc;
      }
      // ---- causal mask (diagonal tiles only) ----
      if (kv0 + 63 > wq0) {
        const int q_abs = wq0 + lq;
#pragma unroll
        for (int kvh = 0; kvh < 2; kvh++)
#pragma unroll
          for (int r = 0; r < 16; r++) {
            const int kv_abs = kv0 + kvh * 32 + (r & 3) + 8 * (r >> 2) + 4 * hi;
            if (kv_abs > q_abs) s[kvh][r] = -1e30f;
          }
      }
      // ---- online softmax: all state per-lane scalar ----
      float mt = s[0][0];
#pragma unroll
      for (int r = 1; r < 16; r++) mt = fmaxf(mt, s[0][r]);
#pragma unroll
      for (int r = 0; r < 16; r++) mt = fmaxf(mt, s[1][r]);
      mt = fmaxf(mt, __shfl_xor(mt, 32));
      const float mnew = fmaxf(mrun, mt);
      const float corr = fexp2(mrun - mnew);
      mrun = mnew;
#pragma unroll
      for (int kvh = 0; kvh < 2; kvh++)
#pragma unroll
        for (int r = 0; r < 16; r++) s[kvh][r] = fexp2(s[kvh][r] - mnew);
      float ps = 0.f;
#pragma unroll
      for (int kvh = 0; kvh < 2; kvh++)
#pragma unroll
        for (int r = 0; r < 16; r++) ps += s[kvh][r];
      ps += __shfl_xor(ps, 32);
      lrun = lrun * corr + ps;
      o0 *= corr;
      o1 *= corr;
      // ---- pack P to bf16 pairs (static indices only) ----
      uint32_t pk[2][8];
#pragma unroll
      for (int kvh = 0; kvh < 2; kvh++)
#pragma unroll
        for (int j = 0; j < 8; j++)
          pk[kvh][j] = pk2bf(s[kvh][2 * j], s[kvh][2 * j + 1]);
      // ---- O^T += V^T P^T ----
#pragma unroll
      for (int c16 = 0; c16 < 4; c16++) {
        const int kvh = c16 >> 1, cl = c16 & 1;
        const uint32_t s0 = (uint32_t)__shfl_xor((int)pk[kvh][4 * cl + 0], 32);
        const uint32_t s1 = (uint32_t)__shfl_xor((int)pk[kvh][4 * cl + 1], 32);
        const uint32_t s2 = (uint32_t)__shfl_xor((int)pk[kvh][4 * cl + 2], 32);
        const uint32_t s3 = (uint32_t)__shfl_xor((int)pk[kvh][4 * cl + 3], 32);
        Frag pb;
        pb.q.x = hi ? s2 : pk[kvh][4 * cl + 0];
        pb.q.y = hi ? s3 : pk[kvh][4 * cl + 1];
        pb.q.z = hi ? pk[kvh][4 * cl + 2] : s0;
        pb.q.w = hi ? pk[kvh][4 * cl + 3] : s1;
#pragma unroll
        for (int dblk = 0; dblk < 2; dblk++) {
          const int row = dblk * 32 + lq;
          Frag vf;
          vf.q = *(const uint4*)(Vt + row * 128 + ((c16 * 32 + hi * 16) ^ ((row & 7) << 4)));
          if (dblk == 0)
            o0 = __builtin_amdgcn_mfma_f32_32x32x16_bf16(vf.v, pb.v, o0, 0, 0, 0);
          else
            o1 = __builtin_amdgcn_mfma_f32_32x32x16_bf16(vf.v, pb.v, o1, 0, 0, 0);
        }
      }
    }
    __builtin_amdgcn_s_barrier();
    cur ^= 1;
  }

  // ---- epilogue: O^T cols are this lane's q row; rows are d ----
  const int bb = bh >> 4, hh = bh & 15;
  const float inv = 1.0f / lrun;
  const int q_abs = wq0 + lq;
  uint16_t* crow = Ctx + ((size_t)bb * TSEQ + q_abs) * DMODEL + hh * 64;
#pragma unroll
  for (int dblk = 0; dblk < 2; dblk++)
#pragma unroll
    for (int g = 0; g < 4; g++) {
      const float a0 = (dblk ? o1[4 * g + 0] : o0[4 * g + 0]) * inv;
      const float a1 = (dblk ? o1[4 * g + 1] : o0[4 * g + 1]) * inv;
      const float a2 = (dblk ? o1[4 * g + 2] : o0[4 * g + 2]) * inv;
      const float a3 = (dblk ? o1[4 * g + 3] : o0[4 * g + 3]) * inv;
      uint2 st;
      st.x = pk2bf(a0, a1);
      st.y = pk2bf(a2, a3);
      *(uint2*)(crow + dblk * 32 + 8 * g + 4 * hi) = st;
    }
}

// ---------------- output projection + bias ----------------

__global__ __launch_bounds__(256) void gemm_out_kernel(const uint16_t* __restrict__ Cb,
    const uint16_t* __restrict__ Wot, const float* __restrict__ bo,
    float* __restrict__ out) {
  __shared__ __align__(16) char lds[32768];
  // bijective XCD swizzle: 512 blocks = 8 chunks x 64
  const int wg = (blockIdx.x & 7) * 64 + (blockIdx.x >> 3);
  const int m0 = (wg & 63) * 128;
  const int n0 = (wg >> 6) * 128;
  f32x4 acc[4][4];
  gemm128_core((const char*)Cb + (size_t)m0 * 2048, (const char*)Wot + (size_t)n0 * 2048,
               lds, acc);

  const int tid = threadIdx.x, wave = tid >> 6, lane = tid & 63;
  const int lr = lane & 15, lg = lane >> 4;
  const int wm0 = (wave >> 1) * 64, wn0 = (wave & 1) * 64;
#pragma unroll
  for (int mi = 0; mi < 4; mi++)
#pragma unroll
    for (int ni = 0; ni < 4; ni++) {
      const int col = n0 + wn0 + ni * 16 + lr;
      const float bias = bo[col];
#pragma unroll
      for (int r = 0; r < 4; r++) {
        const int row = m0 + wm0 + mi * 16 + 4 * lg + r;
        out[(size_t)row * DMODEL + col] = acc[mi][ni][r] + bias;
      }
    }
}

// ---------------- launch ----------------

extern "C" void kernel_launch(void* const* d_in, const int* in_sizes, int n_in,
                              void* d_out, int out_size, void* d_ws, size_t ws_size,
                              hipStream_t stream) {
  const float* x  = (const float*)d_in[0];
  const float* Wq = (const float*)d_in[1];
  const float* Wk = (const float*)d_in[2];
  const float* Wv = (const float*)d_in[3];
  const float* Wo = (const float*)d_in[4];
  const float* bo = (const float*)d_in[5];
  float* out = (float*)d_out;

  char* ws = (char*)d_ws;
  uint16_t* Xb    = (uint16_t*)(ws);                      // 16 MiB [8192][1024]
  uint16_t* Ctx   = (uint16_t*)(ws);                      // aliases Xb (dead after QKV GEMM)
  uint16_t* Wqkvt = (uint16_t*)(ws + (16u << 20));        //  6 MiB [3072][1024] (W^T)
  uint16_t* Wot   = (uint16_t*)(ws + (22u << 20));        //  2 MiB [1024][1024] (Wo^T)
  uint16_t* Qw    = (uint16_t*)(ws + (24u << 20));        // 16 MiB [64][2048][64]
  uint16_t* Kw    = (uint16_t*)(ws + (40u << 20));        // 16 MiB [64][2048][64]
  uint16_t* Vtw   = (uint16_t*)(ws + (56u << 20));        // 16 MiB [64][64][2048]
  (void)ws_size; (void)in_sizes; (void)n_in; (void)out_size;

  cvt_x_kernel<<<8192, 256, 0, stream>>>(x, Xb, 2097152);
  cvt_w_kernel<<<dim3(32, 32, 4), dim3(32, 8), 0, stream>>>(Wq, Wk, Wv, Wo, Wqkvt, Wot);
  gemm_qkv_kernel<<<1536, 256, 0, stream>>>(Xb, Wqkvt, Qw, Kw, Vtw);
  attn_kernel<<<1024, 256, 0, stream>>>(Qw, Kw, Vtw, Ctx);
  gemm_out_kernel<<<512, 256, 0, stream>>>(Ctx, Wot, bo, out);
}

// Round 7
// 192.766 us; speedup vs baseline: 1.1730x; 1.1730x over previous
//
#include <hip/hip_runtime.h>
#include <hip/hip_bf16.h>
#include <stdint.h>

#define TSEQ 2048
#define DMODEL 1024

typedef __attribute__((ext_vector_type(8))) short bf16x8;
typedef __attribute__((ext_vector_type(4))) float f32x4;
typedef __attribute__((ext_vector_type(16))) float f32x16;

union Frag { bf16x8 v; uint4 q; };

__device__ __forceinline__ uint16_t f2bfu(float f) {
  uint32_t u = __builtin_bit_cast(uint32_t, f);
  u += 0x7fffu + ((u >> 16) & 1u);
  return (uint16_t)(u >> 16);
}

__device__ __forceinline__ uint32_t pk2bf(float a, float b) {
  return ((uint32_t)f2bfu(b) << 16) | f2bfu(a);
}

__device__ __forceinline__ float fexp2(float x) {
#if __has_builtin(__builtin_amdgcn_exp2f)
  return __builtin_amdgcn_exp2f(x);
#else
  return exp2f(x);
#endif
}

__device__ __forceinline__ void gload_lds16(const void* g, void* l) {
  __builtin_amdgcn_global_load_lds(
      (const __attribute__((address_space(1))) void*)g,
      (__attribute__((address_space(3))) void*)l, 16, 0, 0);
}

// ---------------- prep kernels ----------------

__global__ __launch_bounds__(256) void cvt_x_kernel(const float* __restrict__ x,
                                                    uint16_t* __restrict__ xb, int n4) {
  int i = blockIdx.x * 256 + threadIdx.x;
  if (i >= n4) return;
  float4 v = ((const float4*)x)[i];
  ushort4 o;
  o.x = f2bfu(v.x); o.y = f2bfu(v.y); o.z = f2bfu(v.z); o.w = f2bfu(v.w);
  ((ushort4*)xb)[i] = o;
}

// dst[n][k] = src[k][n], fp32 -> bf16.  Wq gets 0.125*log2(e) folded in (exp2 softmax).
__global__ __launch_bounds__(256) void cvt_w_kernel(const float* __restrict__ Wq,
    const float* __restrict__ Wk, const float* __restrict__ Wv, const float* __restrict__ Wo,
    uint16_t* __restrict__ Wqkvt, uint16_t* __restrict__ Wot) {
  const float* src = (blockIdx.z == 0) ? Wq : (blockIdx.z == 1) ? Wk
                   : (blockIdx.z == 2) ? Wv : Wo;
  uint16_t* dst = (blockIdx.z < 3) ? (Wqkvt + (size_t)blockIdx.z * DMODEL * DMODEL) : Wot;
  const float wscale = (blockIdx.z == 0) ? 0.125f * 1.4426950408889634f : 1.0f;
  __shared__ float tile[32][33];
  const int x0 = blockIdx.x * 32, y0 = blockIdx.y * 32;
  for (int ii = 0; ii < 4; ii++) {
    int i = threadIdx.y + ii * 8;
    tile[i][threadIdx.x] = src[(size_t)(y0 + i) * DMODEL + x0 + threadIdx.x];
  }
  __syncthreads();
  for (int ii = 0; ii < 4; ii++) {
    int i = threadIdx.y + ii * 8;
    dst[(size_t)(x0 + i) * DMODEL + y0 + threadIdx.x] = f2bfu(tile[threadIdx.x][i] * wscale);
  }
}

// ------- 128x128 GEMM core: 2-phase dbuf, counted vmcnt (T3 minimum) -------
// A row-major [*,1024] bf16, B = W^T rows.  LDS 32 KB (2 x 8KB A + 2 x 8KB B).
// Static x2 unroll: buffer choice is compile-time (rule #20 safe).

__device__ __forceinline__ void gemm_stage(const char* Ab, const char* Bb, int kk,
                                           char* ldsA, char* ldsB, int wave, int lane) {
  const int srow = lane >> 2;        // 0..15 within a 16-row chunk
  const int scol = (lane & 3) * 16;  // byte col within 64B row
#pragma unroll
  for (int c4 = 0; c4 < 2; ++c4) {
    const int c = wave * 2 + c4;     // chunk 0..7 of each tile
    gload_lds16(Ab + (size_t)(c * 16 + srow) * 2048 + kk * 2 + scol, ldsA + c * 1024);
    gload_lds16(Bb + (size_t)(c * 16 + srow) * 2048 + kk * 2 + scol, ldsB + c * 1024);
  }
}

__device__ __forceinline__ void gemm_compute(const char* ldsA, const char* ldsB,
                                             int wm0, int wn0, int lr, int lg,
                                             f32x4 (&acc)[4][4]) {
  Frag a[4], b[4];
#pragma unroll
  for (int mi = 0; mi < 4; mi++)
    a[mi].q = *(const uint4*)(ldsA + (wm0 + mi * 16 + lr) * 64 + lg * 16);
#pragma unroll
  for (int ni = 0; ni < 4; ni++)
    b[ni].q = *(const uint4*)(ldsB + (wn0 + ni * 16 + lr) * 64 + lg * 16);
#pragma unroll
  for (int mi = 0; mi < 4; mi++)
#pragma unroll
    for (int ni = 0; ni < 4; ni++)
      acc[mi][ni] = __builtin_amdgcn_mfma_f32_16x16x32_bf16(a[mi].v, b[ni].v,
                                                            acc[mi][ni], 0, 0, 0);
}

__device__ __forceinline__ void gemm128_core(const char* Ab, const char* Bb,
                                             char* lds,  // 32768 bytes
                                             f32x4 (&acc)[4][4]) {
  const int tid = threadIdx.x;
  const int wave = tid >> 6, lane = tid & 63;
  const int lr = lane & 15, lg = lane >> 4;
  const int wm0 = (wave >> 1) * 64, wn0 = (wave & 1) * 64;
  char* const A0 = lds;          char* const B0 = lds + 8192;
  char* const A1 = lds + 16384;  char* const B1 = lds + 24576;

#pragma unroll
  for (int i = 0; i < 4; i++)
#pragma unroll
    for (int j = 0; j < 4; j++) acc[i][j] = (f32x4){0.f, 0.f, 0.f, 0.f};

  gemm_stage(Ab, Bb, 0, A0, B0, wave, lane);
  for (int it = 0; it < 32; it += 2) {
    // ---- even step: compute buf0, prefetch (it+1) into buf1 ----
    gemm_stage(Ab, Bb, (it + 1) * 32, A1, B1, wave, lane);
    asm volatile("s_waitcnt vmcnt(4)" ::: "memory");  // buf0 landed; buf1 in flight
    __builtin_amdgcn_s_barrier();
    __builtin_amdgcn_sched_barrier(0);
    gemm_compute(A0, B0, wm0, wn0, lr, lg, acc);
    __builtin_amdgcn_s_barrier();                     // buf0 fully consumed

    // ---- odd step: compute buf1, prefetch (it+2) into buf0 ----
    if (it + 2 < 32) {
      gemm_stage(Ab, Bb, (it + 2) * 32, A0, B0, wave, lane);
      asm volatile("s_waitcnt vmcnt(4)" ::: "memory");
    } else {
      asm volatile("s_waitcnt vmcnt(0)" ::: "memory");
    }
    __builtin_amdgcn_s_barrier();
    __builtin_amdgcn_sched_barrier(0);
    gemm_compute(A1, B1, wm0, wn0, lr, lg, acc);
    __builtin_amdgcn_s_barrier();                     // buf1 fully consumed
  }
}

// ---------------- QKV projection GEMM, scatter epilogue ----------------
// Natural 2D grid (m fastest): round-robin across XCDs keeps each XCD's
// concurrent working set (~8 m-tiles + 4 n-tiles ~= 3 MB) inside its 4 MB L2.
// Chunked "XCD swizzle" regressed 4x FETCH (round 5) -- do not reapply.

__global__ __launch_bounds__(256) void gemm_qkv_kernel(const uint16_t* __restrict__ Xb,
    const uint16_t* __restrict__ Wt, uint16_t* __restrict__ Qo,
    uint16_t* __restrict__ Ko, uint16_t* __restrict__ Vt) {
  __shared__ __align__(16) char lds[32768];
  const int m0 = blockIdx.x * 128;
  const int n0 = blockIdx.y * 128;
  f32x4 acc[4][4];
  gemm128_core((const char*)Xb + (size_t)m0 * 2048, (const char*)Wt + (size_t)n0 * 2048,
               lds, acc);

  const int tid = threadIdx.x, wave = tid >> 6, lane = tid & 63;
  const int lr = lane & 15, lg = lane >> 4;
  const int wm0 = (wave >> 1) * 64, wn0 = (wave & 1) * 64;
#pragma unroll
  for (int mi = 0; mi < 4; mi++)
#pragma unroll
    for (int ni = 0; ni < 4; ni++) {
      const int col = n0 + wn0 + ni * 16 + lr;
      const int p = col >> 10, c = col & 1023, h = c >> 6, d = c & 63;
#pragma unroll
      for (int r = 0; r < 4; r++) {
        const int row = m0 + wm0 + mi * 16 + 4 * lg + r;
        const int bb = row >> 11, t = row & 2047;
        const int bh = bb * 16 + h;
        const uint16_t val = f2bfu(acc[mi][ni][r]);
        if (p == 0)      Qo[((size_t)bh * TSEQ + t) * 64 + d] = val;
        else if (p == 1) Ko[((size_t)bh * TSEQ + t) * 64 + d] = val;
        else             Vt[((size_t)bh * 64 + d) * TSEQ + t] = val;
      }
    }
}

// ---------------- flash attention (swapped-QK^T, 32x32 MFMA) ----------------
// 1 block = 128 q rows of one (b,h); 4 waves x 32 q rows (lane&31 = q column).
// KV tile = 64; K tile [64kv][128B], V^T tile [64d][128B], both XOR-swizzled,
// double-buffered via global_load_lds with counted vmcnt.
// NOTE: all private arrays indexed with compile-time constants only (rule #20).

__device__ __forceinline__ void stage_kv(const char* Kb, const char* Vb, int kv0,
                                         char* kdst, char* vdst, int tid) {
  const int w1024 = (tid >> 6) * 1024;
#pragma unroll
  for (int i = 0; i < 2; i++) {
    const int o = i * 4096 + tid * 16;
    const int row = o >> 7;
    const int scol = (o & 127) ^ ((row & 7) << 4);
    gload_lds16(Kb + (size_t)(kv0 + row) * 128 + scol, kdst + i * 4096 + w1024);
    gload_lds16(Vb + (size_t)row * 4096 + kv0 * 2 + scol, vdst + i * 4096 + w1024);
  }
}

__global__ __launch_bounds__(256, 3) void attn_kernel(const uint16_t* __restrict__ Qw,
    const uint16_t* __restrict__ Kw, const uint16_t* __restrict__ Vtw,
    uint16_t* __restrict__ Ctx) {
  const int bid = blockIdx.x;
  const int qt = 15 - (bid >> 6);   // heavy blocks dispatched first
  const int bh = bid & 63;
  const int tid = threadIdx.x;
  const int w = tid >> 6, lane = tid & 63;
  const int lq = lane & 31;         // this lane's q row (within wave tile)
  const int hi = lane >> 5;
  const int wq0 = qt * 128 + w * 32;

  const char* Qb = (const char*)Qw + (size_t)bh * TSEQ * 128;
  const char* Kb = (const char*)Kw + (size_t)bh * TSEQ * 128;
  const char* Vb = (const char*)Vtw + (size_t)bh * 64 * 4096;

  __shared__ __align__(16) char kbuf[2][8192];
  __shared__ __align__(16) char vbuf[2][8192];

  // Q as B-operand fragments: col=q=lane&31, k = kc*16 + 8*hi + e
  Frag qa[4];
#pragma unroll
  for (int kc = 0; kc < 4; kc++)
    qa[kc].q = *(const uint4*)(Qb + (size_t)(wq0 + lq) * 128 + kc * 32 + hi * 16);

  f32x16 o0 = 0.f, o1 = 0.f;   // O^T: col=q (lane), row=d
  float mrun = -1e30f, lrun = 0.f;

  const int nt = 2 * qt + 2;
  stage_kv(Kb, Vb, 0, kbuf[0], vbuf[0], tid);
  int cur = 0;
  for (int t = 0; t < nt; ++t) {
    const int kv0 = t * 64;
    if (t + 1 < nt) {
      stage_kv(Kb, Vb, kv0 + 64, kbuf[cur ^ 1], vbuf[cur ^ 1], tid);
      asm volatile("s_waitcnt vmcnt(4)" ::: "memory");
    } else {
      asm volatile("s_waitcnt vmcnt(0)" ::: "memory");
    }
    __builtin_amdgcn_s_barrier();
    __builtin_amdgcn_sched_barrier(0);

    if (kv0 <= wq0 + 31) {
      const char* Kt = kbuf[cur];
      const char* Vt = vbuf[cur];
      // ---- S^T = K Q^T : per lane one q col, 32 kv rows over 2 halves ----
      f32x16 s[2];
#pragma unroll
      for (int kvh = 0; kvh < 2; kvh++) {
        f32x16 acc = 0.f;
#pragma unroll
        for (int kc = 0; kc < 4; kc++) {
          const int row = kvh * 32 + lq;
          Frag kf;
          kf.q = *(const uint4*)(Kt + row * 128 + ((kc * 32 + hi * 16) ^ ((row & 7) << 4)));
          acc = __builtin_amdgcn_mfma_f32_32x32x16_bf16(kf.v, qa[kc].v, acc, 0, 0, 0);
        }
        s[kvh] = acc;
      }
      // ---- causal mask (diagonal tiles only) ----
      if (kv0 + 63 > wq0) {
        const int q_abs = wq0 + lq;
#pragma unroll
        for (int kvh = 0; kvh < 2; kvh++)
#pragma unroll
          for (int r = 0; r < 16; r++) {
            const int kv_abs = kv0 + kvh * 32 + (r & 3) + 8 * (r >> 2) + 4 * hi;
            if (kv_abs > q_abs) s[kvh][r] = -1e30f;
          }
      }
      // ---- online softmax: all state per-lane scalar ----
      float mt = s[0][0];
#pragma unroll
      for (int r = 1; r < 16; r++) mt = fmaxf(mt, s[0][r]);
#pragma unroll
      for (int r = 0; r < 16; r++) mt = fmaxf(mt, s[1][r]);
      mt = fmaxf(mt, __shfl_xor(mt, 32));
      const float mnew = fmaxf(mrun, mt);
      const float corr = fexp2(mrun - mnew);
      mrun = mnew;
#pragma unroll
      for (int kvh = 0; kvh < 2; kvh++)
#pragma unroll
        for (int r = 0; r < 16; r++) s[kvh][r] = fexp2(s[kvh][r] - mnew);
      float ps = 0.f;
#pragma unroll
      for (int kvh = 0; kvh < 2; kvh++)
#pragma unroll
        for (int r = 0; r < 16; r++) ps += s[kvh][r];
      ps += __shfl_xor(ps, 32);
      lrun = lrun * corr + ps;
      o0 *= corr;
      o1 *= corr;
      // ---- pack P to bf16 pairs (static indices only) ----
      uint32_t pk[2][8];
#pragma unroll
      for (int kvh = 0; kvh < 2; kvh++)
#pragma unroll
        for (int j = 0; j < 8; j++)
          pk[kvh][j] = pk2bf(s[kvh][2 * j], s[kvh][2 * j + 1]);
      // ---- O^T += V^T P^T ----
#pragma unroll
      for (int c16 = 0; c16 < 4; c16++) {
        const int kvh = c16 >> 1, cl = c16 & 1;
        const uint32_t s0 = (uint32_t)__shfl_xor((int)pk[kvh][4 * cl + 0], 32);
        const uint32_t s1 = (uint32_t)__shfl_xor((int)pk[kvh][4 * cl + 1], 32);
        const uint32_t s2 = (uint32_t)__shfl_xor((int)pk[kvh][4 * cl + 2], 32);
        const uint32_t s3 = (uint32_t)__shfl_xor((int)pk[kvh][4 * cl + 3], 32);
        Frag pb;
        pb.q.x = hi ? s2 : pk[kvh][4 * cl + 0];
        pb.q.y = hi ? s3 : pk[kvh][4 * cl + 1];
        pb.q.z = hi ? pk[kvh][4 * cl + 2] : s0;
        pb.q.w = hi ? pk[kvh][4 * cl + 3] : s1;
#pragma unroll
        for (int dblk = 0; dblk < 2; dblk++) {
          const int row = dblk * 32 + lq;
          Frag vf;
          vf.q = *(const uint4*)(Vt + row * 128 + ((c16 * 32 + hi * 16) ^ ((row & 7) << 4)));
          if (dblk == 0)
            o0 = __builtin_amdgcn_mfma_f32_32x32x16_bf16(vf.v, pb.v, o0, 0, 0, 0);
          else
            o1 = __builtin_amdgcn_mfma_f32_32x32x16_bf16(vf.v, pb.v, o1, 0, 0, 0);
        }
      }
    }
    __builtin_amdgcn_s_barrier();
    cur ^= 1;
  }

  // ---- epilogue: O^T cols are this lane's q row; rows are d ----
  const int bb = bh >> 4, hh = bh & 15;
  const float inv = 1.0f / lrun;
  const int q_abs = wq0 + lq;
  uint16_t* crow = Ctx + ((size_t)bb * TSEQ + q_abs) * DMODEL + hh * 64;
#pragma unroll
  for (int dblk = 0; dblk < 2; dblk++)
#pragma unroll
    for (int g = 0; g < 4; g++) {
      const float a0 = (dblk ? o1[4 * g + 0] : o0[4 * g + 0]) * inv;
      const float a1 = (dblk ? o1[4 * g + 1] : o0[4 * g + 1]) * inv;
      const float a2 = (dblk ? o1[4 * g + 2] : o0[4 * g + 2]) * inv;
      const float a3 = (dblk ? o1[4 * g + 3] : o0[4 * g + 3]) * inv;
      uint2 st;
      st.x = pk2bf(a0, a1);
      st.y = pk2bf(a2, a3);
      *(uint2*)(crow + dblk * 32 + 8 * g + 4 * hi) = st;
    }
}

// ---------------- output projection + bias ----------------

__global__ __launch_bounds__(256) void gemm_out_kernel(const uint16_t* __restrict__ Cb,
    const uint16_t* __restrict__ Wot, const float* __restrict__ bo,
    float* __restrict__ out) {
  __shared__ __align__(16) char lds[32768];
  const int m0 = blockIdx.x * 128;
  const int n0 = blockIdx.y * 128;
  f32x4 acc[4][4];
  gemm128_core((const char*)Cb + (size_t)m0 * 2048, (const char*)Wot + (size_t)n0 * 2048,
               lds, acc);

  const int tid = threadIdx.x, wave = tid >> 6, lane = tid & 63;
  const int lr = lane & 15, lg = lane >> 4;
  const int wm0 = (wave >> 1) * 64, wn0 = (wave & 1) * 64;
#pragma unroll
  for (int mi = 0; mi < 4; mi++)
#pragma unroll
    for (int ni = 0; ni < 4; ni++) {
      const int col = n0 + wn0 + ni * 16 + lr;
      const float bias = bo[col];
#pragma unroll
      for (int r = 0; r < 4; r++) {
        const int row = m0 + wm0 + mi * 16 + 4 * lg + r;
        out[(size_t)row * DMODEL + col] = acc[mi][ni][r] + bias;
      }
    }
}

// ---------------- launch ----------------

extern "C" void kernel_launch(void* const* d_in, const int* in_sizes, int n_in,
                              void* d_out, int out_size, void* d_ws, size_t ws_size,
                              hipStream_t stream) {
  const float* x  = (const float*)d_in[0];
  const float* Wq = (const float*)d_in[1];
  const float* Wk = (const float*)d_in[2];
  const float* Wv = (const float*)d_in[3];
  const float* Wo = (const float*)d_in[4];
  const float* bo = (const float*)d_in[5];
  float* out = (float*)d_out;

  char* ws = (char*)d_ws;
  uint16_t* Xb    = (uint16_t*)(ws);                      // 16 MiB [8192][1024]
  uint16_t* Ctx   = (uint16_t*)(ws);                      // aliases Xb (dead after QKV GEMM)
  uint16_t* Wqkvt = (uint16_t*)(ws + (16u << 20));        //  6 MiB [3072][1024] (W^T)
  uint16_t* Wot   = (uint16_t*)(ws + (22u << 20));        //  2 MiB [1024][1024] (Wo^T)
  uint16_t* Qw    = (uint16_t*)(ws + (24u << 20));        // 16 MiB [64][2048][64]
  uint16_t* Kw    = (uint16_t*)(ws + (40u << 20));        // 16 MiB [64][2048][64]
  uint16_t* Vtw   = (uint16_t*)(ws + (56u << 20));        // 16 MiB [64][64][2048]
  (void)ws_size; (void)in_sizes; (void)n_in; (void)out_size;

  cvt_x_kernel<<<8192, 256, 0, stream>>>(x, Xb, 2097152);
  cvt_w_kernel<<<dim3(32, 32, 4), dim3(32, 8), 0, stream>>>(Wq, Wk, Wv, Wo, Wqkvt, Wot);
  gemm_qkv_kernel<<<dim3(64, 24), 256, 0, stream>>>(Xb, Wqkvt, Qw, Kw, Vtw);
  attn_kernel<<<1024, 256, 0, stream>>>(Qw, Kw, Vtw, Ctx);
  gemm_out_kernel<<<dim3(64, 8), 256, 0, stream>>>(Ctx, Wot, bo, out);
}